// Round 1
// baseline (4822.281 us; speedup 1.0000x reference)
//
#include <hip/hip_runtime.h>

#define B_ 256
#define T_ 256
#define E_ 512
#define U_ 1024
#define G_ 4096   // 4*U
#define V_ 50000
#define TC_ 32    // timesteps per x_proj chunk
#define NCH_ 8    // T_/TC_

typedef __bf16 bf16x8 __attribute__((ext_vector_type(8)));
typedef float f32x4 __attribute__((ext_vector_type(4)));
typedef unsigned short us8 __attribute__((ext_vector_type(8)));

__device__ __forceinline__ unsigned short f2bf(float f) {
  union { float f; unsigned u; } v; v.f = f;
  unsigned u = v.u;
  u = (u + 0x7FFFu + ((u >> 16) & 1u)) >> 16;   // RNE
  return (unsigned short)u;
}
__device__ __forceinline__ float bf2f(unsigned short h) {
  union { unsigned u; float f; } v; v.u = ((unsigned)h) << 16;
  return v.f;
}
__device__ __forceinline__ float sigm_(float x) { return 1.f / (1.f + __expf(-x)); }
__device__ __forceinline__ float tanh_(float x) { return 2.f / (1.f + __expf(-2.f * x)) - 1.f; }

__device__ __forceinline__ void gload16(const void* g, void* l) {
  __builtin_amdgcn_global_load_lds((const __attribute__((address_space(1))) void*)g,
                                   (__attribute__((address_space(3))) void*)l, 16, 0, 0);
}

// ---------------- prep: f32 -> bf16 (row-major) ----------------
__global__ void cvt_bf16_kernel(const float* __restrict__ in, unsigned short* __restrict__ out, long n) {
  long i = (((long)blockIdx.x * blockDim.x) + threadIdx.x) << 3;
  long stride = ((long)gridDim.x * blockDim.x) << 3;
  for (; i < n; i += stride) {
    float4 x = *(const float4*)(in + i);
    float4 y = *(const float4*)(in + i + 4);
    us8 v;
    v[0] = f2bf(x.x); v[1] = f2bf(x.y); v[2] = f2bf(x.z); v[3] = f2bf(x.w);
    v[4] = f2bf(y.x); v[5] = f2bf(y.y); v[6] = f2bf(y.z); v[7] = f2bf(y.w);
    *(us8*)(out + i) = v;
  }
}

// ---------------- prep: pack W [K][4096] f32 -> [K/8][4096][8] bf16 ----------------
__global__ void pack_b_kernel(const float* __restrict__ w, unsigned short* __restrict__ out, int total) {
  int t = blockIdx.x * blockDim.x + threadIdx.x;   // over (K/8)*4096
  if (t >= total) return;
  int kb = t >> 12, n = t & 4095;
  us8 v;
#pragma unroll
  for (int ki = 0; ki < 8; ki++) v[ki] = f2bf(w[(size_t)(kb * 8 + ki) * G_ + n]);
  *(us8*)(out + (size_t)t * 8) = v;
}

// ---------------- x_proj: gather(emb) @ Wx + b -> bf16 [TC*B][G] ----------------
#define XP_BM 128
#define XP_BN 128
#define XP_KC 64
__global__ __launch_bounds__(256, 2) void xproj_kernel(
    const int* __restrict__ sent, const unsigned short* __restrict__ embb,
    const unsigned short* __restrict__ wxp, const float* __restrict__ bias,
    unsigned short* __restrict__ xp, int t0)
{
  __shared__ __align__(16) unsigned short sA[2][XP_BM * XP_KC];
  __shared__ __align__(16) unsigned short sB[2][XP_KC * XP_BN];
  __shared__ int tok[XP_BM];

  const int tid = threadIdx.x;
  const int lane = tid & 63;
  const int wid = tid >> 6;
  const int m0 = blockIdx.x * XP_BM;   // row = tl*256 + b  (chunk-local)
  const int n0 = blockIdx.y * XP_BN;

  if (tid < XP_BM) {
    int row = m0 + tid;
    int tl = row >> 8, b = row & 255;
    tok[tid] = sent[b * T_ + t0 + tl];
  }
  __syncthreads();

  auto stageA = [&](int bf, int kc) {
#pragma unroll
    for (int ii = 0; ii < 4; ii++) {
      int i = wid * 4 + ii;                 // 16 issues, 8 rows each
      int m = i * 8 + (lane >> 3);
      int cl = lane & 7;                    // linear 16B-chunk within row
      const unsigned short* src = embb + (size_t)tok[m] * E_ + kc + ((cl ^ (m & 7)) << 3);
      gload16(src, &sA[bf][i * 512]);
    }
  };
  auto stageB = [&](int bf, int kc) {
    int kb0 = kc >> 3;
#pragma unroll
    for (int jj = 0; jj < 4; jj++) {
      int j = wid * 4 + jj;                 // 16 issues
      int r = j >> 1;
      int nl = ((j & 1) << 6) + lane;       // linear n slot 0..127
      int n = nl ^ r;                       // swizzled source column
      const unsigned short* src = wxp + ((size_t)(kb0 + r) * G_ + n0 + n) * 8;
      gload16(src, &sB[bf][j * 512]);
    }
  };

  f32x4 acc[4][4];
#pragma unroll
  for (int i = 0; i < 4; i++)
#pragma unroll
    for (int j = 0; j < 4; j++) acc[i][j] = f32x4{0.f, 0.f, 0.f, 0.f};

  const int wm = wid >> 1, wn = wid & 1;

  stageA(0, 0); stageB(0, 0);
  for (int it = 0; it < E_ / XP_KC; it++) {   // 8
    int bf = it & 1;
    __syncthreads();                          // staged buf ready (vmcnt drained)
    if (it < E_ / XP_KC - 1) { stageA(bf ^ 1, (it + 1) * XP_KC); stageB(bf ^ 1, (it + 1) * XP_KC); }
#pragma unroll
    for (int kk = 0; kk < 2; kk++) {          // K=32 sub-steps
      int c = (kk << 2) + (lane >> 4);
      bf16x8 a[4], b[4];
#pragma unroll
      for (int ms = 0; ms < 4; ms++) {
        int m = (wm << 6) + (ms << 4) + (lane & 15);
        a[ms] = *(const bf16x8*)&sA[bf][m * 64 + ((c ^ (m & 7)) << 3)];
      }
#pragma unroll
      for (int ns = 0; ns < 4; ns++) {
        int n = (wn << 6) + (ns << 4) + (lane & 15);
        b[ns] = *(const bf16x8*)&sB[bf][((c << 7) + (n ^ c)) << 3];
      }
#pragma unroll
      for (int ms = 0; ms < 4; ms++)
#pragma unroll
        for (int ns = 0; ns < 4; ns++)
          acc[ms][ns] = __builtin_amdgcn_mfma_f32_16x16x32_bf16(a[ms], b[ns], acc[ms][ns], 0, 0, 0);
    }
  }

  // epilogue: D row=(lane>>4)*4+reg, col=lane&15 ; rows are already t-major chunk rows
#pragma unroll
  for (int ns = 0; ns < 4; ns++) {
    int col = n0 + (wn << 6) + (ns << 4) + (lane & 15);
    float bv = bias[col];
#pragma unroll
    for (int ms = 0; ms < 4; ms++) {
      int rbase = m0 + (wm << 6) + (ms << 4) + ((lane >> 4) << 2);
#pragma unroll
      for (int rr = 0; rr < 4; rr++)
        xp[(size_t)(rbase + rr) * G_ + col] = f2bf(acc[ms][ns][rr] + bv);
    }
  }
}

// ---------------- one LSTM timestep: gates = xp + h@Wh ; update c,h ----------------
#define LS_KC 64
__global__ __launch_bounds__(256, 2) void lstm_step_kernel(
    const unsigned short* __restrict__ xp_t,   // [B][G] bf16 (bias included)
    const unsigned short* __restrict__ whp,    // packed Wh
    const unsigned short* __restrict__ h_in,   // [B][U] bf16
    unsigned short* __restrict__ h_out,        // [B][U] bf16
    float* __restrict__ c_state)               // [B][U] f32
{
  __shared__ __align__(16) unsigned short sA[2][64 * LS_KC];      // 8KB x2
  __shared__ __align__(16) unsigned short sB[2][4][8 * 32 * 8];   // 4KB/strip x4 x2
  __shared__ float sG[4][64][32];                                 // 32KB gate exchange

  const int tid = threadIdx.x, lane = tid & 63, w = tid >> 6;     // wave = gate
  const int xcd = blockIdx.x & 7, rb = blockIdx.x >> 3;
  const int u0 = (xcd * 4 + (rb & 3)) * 32;    // same-XCD blocks share u-range -> Wh L2-hot
  const int m0 = (rb >> 2) * 64;

  auto stageA = [&](int bf, int kc) {
#pragma unroll
    for (int ii = 0; ii < 2; ii++) {
      int i = w * 2 + ii;
      int m = i * 8 + (lane >> 3), cl = lane & 7;
      const unsigned short* src = h_in + (size_t)(m0 + m) * U_ + kc + ((cl ^ (m & 7)) << 3);
      gload16(src, &sA[bf][i * 512]);
    }
  };
  auto stageB = [&](int bf, int kc) {
    int kb0 = kc >> 3;
#pragma unroll
    for (int j = 0; j < 4; j++) {
      int r = (j << 1) + (lane >> 5);
      int nl = lane & 31, n = nl ^ r;
      const unsigned short* src = whp + ((size_t)(kb0 + r) * G_ + w * U_ + u0 + n) * 8;
      gload16(src, &sB[bf][w][j * 512]);
    }
  };

  f32x4 acc[4][2];
#pragma unroll
  for (int i = 0; i < 4; i++) { acc[i][0] = f32x4{0.f,0.f,0.f,0.f}; acc[i][1] = f32x4{0.f,0.f,0.f,0.f}; }

  stageA(0, 0); stageB(0, 0);
  for (int it = 0; it < U_ / LS_KC; it++) {    // 16
    int bf = it & 1;
    __syncthreads();
    if (it < U_ / LS_KC - 1) { stageA(bf ^ 1, (it + 1) * LS_KC); stageB(bf ^ 1, (it + 1) * LS_KC); }
#pragma unroll
    for (int kk = 0; kk < 2; kk++) {
      int c = (kk << 2) + (lane >> 4);
      bf16x8 a[4], b[2];
#pragma unroll
      for (int ms = 0; ms < 4; ms++) {
        int m = (ms << 4) + (lane & 15);
        a[ms] = *(const bf16x8*)&sA[bf][m * 64 + ((c ^ (m & 7)) << 3)];
      }
#pragma unroll
      for (int ns = 0; ns < 2; ns++) {
        int n = (ns << 4) + (lane & 15);
        b[ns] = *(const bf16x8*)&sB[bf][w][((c << 5) + (n ^ c)) << 3];
      }
#pragma unroll
      for (int ms = 0; ms < 4; ms++)
#pragma unroll
        for (int ns = 0; ns < 2; ns++)
          acc[ms][ns] = __builtin_amdgcn_mfma_f32_16x16x32_bf16(a[ms], b[ns], acc[ms][ns], 0, 0, 0);
    }
  }

  // gate exchange through LDS
#pragma unroll
  for (int ms = 0; ms < 4; ms++)
#pragma unroll
    for (int ns = 0; ns < 2; ns++)
#pragma unroll
      for (int rg = 0; rg < 4; rg++) {
        int m = (ms << 4) + ((lane >> 4) << 2) + rg;
        int u = (ns << 4) + (lane & 15);
        sG[w][m][u] = acc[ms][ns][rg];
      }
  __syncthreads();

  // elementwise c/h update: 64x32 elems, 8 per thread
#pragma unroll
  for (int kk = 0; kk < 8; kk++) {
    int idx = (kk << 8) + tid;
    int m = idx >> 5, u = idx & 31;
    int gm = m0 + m, gu = u0 + u;
    const unsigned short* xr = xp_t + (size_t)gm * G_ + gu;
    float gi = sG[0][m][u] + bf2f(xr[0]);
    float gf = sG[1][m][u] + bf2f(xr[U_]);
    float gg = sG[2][m][u] + bf2f(xr[2 * U_]);
    float go = sG[3][m][u] + bf2f(xr[3 * U_]);
    float iv = sigm_(gi), fv = sigm_(gf), gv = tanh_(gg), ov = sigm_(go);
    size_t ci = (size_t)gm * U_ + gu;
    float cv = fv * c_state[ci] + iv * gv;
    c_state[ci] = cv;
    h_out[ci] = f2bf(ov * tanh_(cv));
  }
}

// ---------------- head: sigmoid((h@W1+b1)@W2+b2) ----------------
__global__ __launch_bounds__(256) void dense_kernel(
    const unsigned short* __restrict__ h, const float* __restrict__ W1, const float* __restrict__ b1,
    const float* __restrict__ W2, const float* __restrict__ b2, float* __restrict__ out)
{
  int tid = threadIdx.x, j = tid & 63, kq = tid >> 6;
  const unsigned short* hr = h + (size_t)blockIdx.x * U_;
  float s = 0.f;
#pragma unroll 8
  for (int k = kq * 256; k < kq * 256 + 256; k++) s += bf2f(hr[k]) * W1[k * 64 + j];
  __shared__ float red[4][64];
  red[kq][j] = s;
  __syncthreads();
  if (tid < 64) {
    float hid = red[0][j] + red[1][j] + red[2][j] + red[3][j] + b1[j];
    float p = hid * W2[j];
#pragma unroll
    for (int off = 32; off; off >>= 1) p += __shfl_down(p, off, 64);
    if (j == 0) out[blockIdx.x] = 1.f / (1.f + __expf(-(p + b2[0])));
  }
}

extern "C" void kernel_launch(void* const* d_in, const int* in_sizes, int n_in,
                              void* d_out, int out_size, void* d_ws, size_t ws_size,
                              hipStream_t stream) {
  const int*   sent = (const int*)d_in[0];
  const float* emb  = (const float*)d_in[1];
  const float* Wx   = (const float*)d_in[2];
  const float* Wh   = (const float*)d_in[3];
  const float* bias = (const float*)d_in[4];
  const float* W1   = (const float*)d_in[5];
  const float* b1   = (const float*)d_in[6];
  const float* W2   = (const float*)d_in[7];
  const float* b2   = (const float*)d_in[8];
  float* out = (float*)d_out;

  char* ws = (char*)d_ws;
  size_t off = 0;
  auto alloc = [&](size_t bytes) { void* p = ws + off; off += (bytes + 255) & ~(size_t)255; return p; };
  unsigned short* embb = (unsigned short*)alloc((size_t)V_ * E_ * 2);   // 51.2 MB
  unsigned short* wxp  = (unsigned short*)alloc((size_t)E_ * G_ * 2);   // 4.2 MB
  unsigned short* whp  = (unsigned short*)alloc((size_t)U_ * G_ * 2);   // 8.4 MB
  unsigned short* xpc  = (unsigned short*)alloc((size_t)TC_ * B_ * G_ * 2); // 67 MB
  unsigned short* hbuf = (unsigned short*)alloc((size_t)2 * B_ * U_ * 2);
  float*          cst  = (float*)alloc((size_t)B_ * U_ * 4);

  // prep
  hipLaunchKernelGGL(cvt_bf16_kernel, dim3(12500), dim3(256), 0, stream, emb, embb, (long)V_ * E_);
  hipLaunchKernelGGL(pack_b_kernel, dim3((E_ / 8) * G_ / 256), dim3(256), 0, stream, Wx, wxp, (E_ / 8) * G_);
  hipLaunchKernelGGL(pack_b_kernel, dim3((U_ / 8) * G_ / 256), dim3(256), 0, stream, Wh, whp, (U_ / 8) * G_);
  hipMemsetAsync(hbuf, 0, (size_t)B_ * U_ * 2, stream);   // h0 = 0 (buffer 0)
  hipMemsetAsync(cst, 0, (size_t)B_ * U_ * 4, stream);    // c0 = 0

  for (int ch = 0; ch < NCH_; ch++) {
    hipLaunchKernelGGL(xproj_kernel, dim3(TC_ * B_ / XP_BM, G_ / XP_BN), dim3(256), 0, stream,
                       sent, embb, wxp, bias, xpc, ch * TC_);
    for (int tl = 0; tl < TC_; tl++) {
      int t = ch * TC_ + tl;
      hipLaunchKernelGGL(lstm_step_kernel, dim3(128), dim3(256), 0, stream,
                         xpc + (size_t)tl * B_ * G_, whp,
                         hbuf + (size_t)(t & 1) * B_ * U_,
                         hbuf + (size_t)((t + 1) & 1) * B_ * U_, cst);
    }
  }
  hipLaunchKernelGGL(dense_kernel, dim3(B_), dim3(256), 0, stream,
                     hbuf /* t=256 -> buffer 0 */, W1, b1, W2, b2, out);
}